// Round 7
// baseline (39.637 us; speedup 1.0000x reference)
//
#include <hip/hip_runtime.h>

// KAConv: out[b,f,h,w] = sum_{c,p} P_fcp(v) / (1 + |Q_fcp(v)|),
//   v = x[b,c,h+i-1,w+j-1] (zero pad), p = i*3+j
// Shapes: x[4,16,64,64], A[16,16,9,6], Bc[16,16,9,4], out[4,16,64,64], f32.
//
// Round 7 (one change vs round 4): coefficient delivery restructured so the
// scalar loads can software-pipeline. Prep kernel packs coeffs into aligned
// 32-dword groups (one tap-row each: 18 A + 12 B + 2 pad); main kernel
// double-buffers two groups in SGPRs (64 SGPRs, fits the file -> no chunked
// s_load + lgkmcnt serialization inside the tap loop) with prefetch
// distance 2 groups (~290 cyc). Windows prefetched one c ahead.

#define BB   4
#define CIN  16
#define COUT 16
#define HH   64
#define WW   64

// ---------------- prep: repack coefficients into aligned groups -------------
__global__ __launch_bounds__(256) void repack_kernel(
    const float* __restrict__ A,    // [F*C][9][6]
    const float* __restrict__ Bc,   // [F*C][9][4]
    float* __restrict__ P)          // [F*C][3][32]
{
    const int i = blockIdx.x * 256 + threadIdx.x;
    if (i >= COUT * CIN * 3 * 32) return;
    const int k  = i & 31;          // dword within group
    const int s  = i >> 5;          // (f*16+c)*3 + g
    const int g  = s % 3;
    const int fc = s / 3;
    float val = 0.0f;
    if (k < 18)      val = A[fc * 54 + g * 18 + k];          // taps 3g..3g+2, 6 ea
    else if (k < 30) val = Bc[fc * 36 + g * 12 + (k - 18)];  // taps 3g..3g+2, 4 ea
    P[i] = val;
}

// ---------------- main ------------------------------------------------------
static __device__ __forceinline__ void loadw(const float* __restrict__ xb, int c,
                                             int r0, int w, float v[4][3]) {
    const float* __restrict__ xc = xb + c * (HH * WW);
    #pragma unroll
    for (int ri = 0; ri < 4; ++ri) {
        const int hh   = r0 - 1 + ri;
        const bool okh = (hh >= 0) & (hh < HH);
        #pragma unroll
        for (int j = 0; j < 3; ++j) {
            const int wj  = w + j - 1;
            const bool ok = okh & (wj >= 0) & (wj < WW);
            v[ri][j] = ok ? xc[hh * WW + wj] : 0.0f;
        }
    }
}

template <int G>
static __device__ __forceinline__ void grp(const float (&buf)[32],
                                           const float (&vv)[4][3],
                                           float& acc0, float& acc1)
{
    #pragma unroll
    for (int t = 0; t < 3; ++t) {
        const float va = vv[G][t];
        const float vb = vv[G + 1][t];
        const float a0 = buf[t*6+0], a1 = buf[t*6+1], a2 = buf[t*6+2];
        const float a3 = buf[t*6+3], a4 = buf[t*6+4], a5 = buf[t*6+5];
        const float b1 = buf[18+t*4+0], b2 = buf[18+t*4+1];
        const float b3 = buf[18+t*4+2], b4 = buf[18+t*4+3];

        float P0 = a5, P1 = a5;
        P0 = fmaf(P0, va, a4);  P1 = fmaf(P1, vb, a4);
        P0 = fmaf(P0, va, a3);  P1 = fmaf(P1, vb, a3);
        P0 = fmaf(P0, va, a2);  P1 = fmaf(P1, vb, a2);
        P0 = fmaf(P0, va, a1);  P1 = fmaf(P1, vb, a1);
        P0 = fmaf(P0, va, a0);  P1 = fmaf(P1, vb, a0);

        float q0 = b4, q1 = b4;
        q0 = fmaf(q0, va, b3);  q1 = fmaf(q1, vb, b3);
        q0 = fmaf(q0, va, b2);  q1 = fmaf(q1, vb, b2);
        q0 = fmaf(q0, va, b1);  q1 = fmaf(q1, vb, b1);
        q0 *= va;               q1 *= vb;

        const float d0 = 1.0f + fabsf(q0);
        const float d1 = 1.0f + fabsf(q1);
        acc0 = fmaf(P0, __builtin_amdgcn_rcpf(d0), acc0);
        acc1 = fmaf(P1, __builtin_amdgcn_rcpf(d1), acc1);
    }
}

__global__ __launch_bounds__(512, 4) void KAConv_kernel(
    const float* __restrict__ x,    // [B,C,H,W]
    const float* __restrict__ cw,   // packed coeffs [F*C][3][32]
    float* __restrict__ out)        // [B,F,H,W]
{
    const int blk   = blockIdx.x;
    const int f     = blk & 15;
    const int rtile = (blk >> 4) & 7;
    const int b     = blk >> 7;

    const int tid  = threadIdx.x;
    const int team = __builtin_amdgcn_readfirstlane(tid >> 8);   // 0 or 1
    const int tp   = tid & 255;
    const int w    = tp & 63;
    const int r0   = (rtile << 3) + ((tp >> 6) << 1);  // rows r0, r0+1
    const int c0   = team << 3;

    const float* __restrict__ xb = x  + (b * CIN + c0) * (HH * WW);
    const float* __restrict__ cp = cw + (f * CIN + c0) * 96;   // 24 groups x 32

    __shared__ float sRed[2 * 256];

    // Preload groups 0 and 1 (uniform address -> s_load_dwordx16 pairs).
    float bufA[32], bufB[32];
    #pragma unroll
    for (int k = 0; k < 32; ++k) bufA[k] = cp[k];
    #pragma unroll
    for (int k = 0; k < 32; ++k) bufB[k] = cp[32 + k];

    float vv[4][3], vn[4][3];
    loadw(xb, 0, r0, w, vv);

    float acc0 = 0.0f, acc1 = 0.0f;

    // 24 flattened (c,g) steps, fully unrolled; CUR alternates A/B.
    // At step S: CUR holds group S; after computing, reload CUR with S+2.
#define STEP(S, CUR)                                                        \
    {                                                                       \
        constexpr int c_ = (S) / 3, g_ = (S) % 3;                           \
        if constexpr (g_ == 0 && c_ > 0) {                                  \
            _Pragma("unroll") for (int ri_ = 0; ri_ < 4; ++ri_)             \
                _Pragma("unroll") for (int j_ = 0; j_ < 3; ++j_)            \
                    vv[ri_][j_] = vn[ri_][j_];                              \
        }                                                                   \
        if constexpr (g_ == 1 && c_ + 1 < 8) loadw(xb, c_ + 1, r0, w, vn);  \
        grp<g_>(CUR, vv, acc0, acc1);                                       \
        if constexpr ((S) + 2 < 24) {                                       \
            _Pragma("unroll") for (int k_ = 0; k_ < 32; ++k_)               \
                CUR[k_] = cp[((S) + 2) * 32 + k_];                          \
        }                                                                   \
    }

    STEP(0,  bufA) STEP(1,  bufB) STEP(2,  bufA) STEP(3,  bufB)
    STEP(4,  bufA) STEP(5,  bufB) STEP(6,  bufA) STEP(7,  bufB)
    STEP(8,  bufA) STEP(9,  bufB) STEP(10, bufA) STEP(11, bufB)
    STEP(12, bufA) STEP(13, bufB) STEP(14, bufA) STEP(15, bufB)
    STEP(16, bufA) STEP(17, bufB) STEP(18, bufA) STEP(19, bufB)
    STEP(20, bufA) STEP(21, bufB) STEP(22, bufA) STEP(23, bufB)
#undef STEP

    // Reduce the two channel-halves: team 1 -> LDS, team 0 adds and stores.
    if (team == 1) {
        sRed[tp]       = acc0;
        sRed[256 + tp] = acc1;
    }
    __syncthreads();
    if (team == 0) {
        acc0 += sRed[tp];
        acc1 += sRed[256 + tp];
        float* __restrict__ of = out + ((b * COUT + f) * HH) * WW + w;
        of[r0 * WW]       = acc0;
        of[(r0 + 1) * WW] = acc1;
    }
}

extern "C" void kernel_launch(void* const* d_in, const int* in_sizes, int n_in,
                              void* d_out, int out_size, void* d_ws, size_t ws_size,
                              hipStream_t stream) {
    const float* x  = (const float*)d_in[0];
    const float* A  = (const float*)d_in[1];
    const float* Bc = (const float*)d_in[2];
    float* out = (float*)d_out;
    float* cw  = (float*)d_ws;      // 16*16*3*32 floats = 98.3 KB

    const int nrep = COUT * CIN * 3 * 32;
    repack_kernel<<<(nrep + 255) / 256, 256, 0, stream>>>(A, Bc, cw);

    const int grid = BB * (HH / 8) * COUT;   // 512 blocks
    KAConv_kernel<<<grid, 512, 0, stream>>>(x, cw, out);
}

// Round 8
// 19.967 us; speedup vs baseline: 1.9852x; 1.9852x over previous
//
#include <hip/hip_runtime.h>

// KAConv: out[b,f,h,w] = sum_{c,p} P_fcp(v) / (1 + |Q_fcp(v)|),
//   v = x[b,c,h+i-1,w+j-1] (zero pad), p = i*3+j
// Shapes: x[4,16,64,64], A[16,16,9,6], Bc[16,16,9,4], out[4,16,64,64], f32.
//
// Round 8: one wave = one input channel. The SGPR file is PER-WAVE, so with
// 16 waves/block (block = 1024 thr) each wave loads its channel's 90
// coefficient dwords ONCE (hoisted s_load_dwordx16 group, one lgkmcnt wait
// per kernel) and keeps them resident for the whole kernel — eliminating the
// per-c-iteration chunked scalar reloads that stalled r1-r5 at ~40% duty.
// Channel sum across the block's 16 waves via an 8 KB LDS matrix.

#define BB   4
#define CIN  16
#define COUT 16
#define HH   64
#define WW   64

__global__ __launch_bounds__(1024, 8) void KAConv_kernel(
    const float* __restrict__ x,    // [B,C,H,W]
    const float* __restrict__ A,    // [F,C,9,6]
    const float* __restrict__ Bc,   // [F,C,9,4]
    float* __restrict__ out)        // [B,F,H,W]
{
    // grid = b(4) x rowpair(32) x f(16) = 2048 blocks; block = 16 waves.
    const int blk = blockIdx.x;
    const int f   = blk & 15;
    const int rp  = (blk >> 4) & 31;
    const int b   = blk >> 9;

    const int tid  = threadIdx.x;
    const int cw   = __builtin_amdgcn_readfirstlane(tid >> 6);  // wave = channel
    const int lane = tid & 63;
    const int w    = lane;
    const int r0   = rp << 1;                                   // rows r0, r0+1

    // This wave's coefficients: uniform addresses -> s_load, hoisted, resident.
    const float* __restrict__ Ac = A  + (f * CIN + cw) * 54;
    const float* __restrict__ Bq = Bc + (f * CIN + cw) * 36;
    const float* __restrict__ xc = x  + (b * CIN + cw) * (HH * WW);

    // 4 window rows (r0-1 .. r0+2) x 3 col offsets, zero-padded.
    float vv[4][3];
    #pragma unroll
    for (int ri = 0; ri < 4; ++ri) {
        const int hh   = r0 - 1 + ri;
        const bool okh = (hh >= 0) & (hh < HH);
        #pragma unroll
        for (int j = 0; j < 3; ++j) {
            const int wj  = w + j - 1;
            const bool ok = okh & (wj >= 0) & (wj < WW);
            vv[ri][j] = ok ? xc[hh * WW + wj] : 0.0f;
        }
    }

    float acc0 = 0.0f, acc1 = 0.0f;

    #pragma unroll
    for (int p = 0; p < 9; ++p) {
        const int i = p / 3;            // compile-time (full unroll)
        const int j = p % 3;
        const float va = vv[i][j];
        const float vb = vv[i + 1][j];
        const float a0 = Ac[p * 6 + 0], a1 = Ac[p * 6 + 1], a2 = Ac[p * 6 + 2];
        const float a3 = Ac[p * 6 + 3], a4 = Ac[p * 6 + 4], a5 = Ac[p * 6 + 5];
        const float b1 = Bq[p * 4 + 0], b2 = Bq[p * 4 + 1];
        const float b3 = Bq[p * 4 + 2], b4 = Bq[p * 4 + 3];

        float P0 = a5, P1 = a5;
        P0 = fmaf(P0, va, a4);  P1 = fmaf(P1, vb, a4);
        P0 = fmaf(P0, va, a3);  P1 = fmaf(P1, vb, a3);
        P0 = fmaf(P0, va, a2);  P1 = fmaf(P1, vb, a2);
        P0 = fmaf(P0, va, a1);  P1 = fmaf(P1, vb, a1);
        P0 = fmaf(P0, va, a0);  P1 = fmaf(P1, vb, a0);

        float q0 = b4, q1 = b4;
        q0 = fmaf(q0, va, b3);  q1 = fmaf(q1, vb, b3);
        q0 = fmaf(q0, va, b2);  q1 = fmaf(q1, vb, b2);
        q0 = fmaf(q0, va, b1);  q1 = fmaf(q1, vb, b1);
        q0 *= va;               q1 *= vb;

        const float d0 = 1.0f + fabsf(q0);
        const float d1 = 1.0f + fabsf(q1);
        acc0 = fmaf(P0, __builtin_amdgcn_rcpf(d0), acc0);
        acc1 = fmaf(P1, __builtin_amdgcn_rcpf(d1), acc1);
    }

    // Reduce the 16 per-channel partials: sRed[channel][pixel], then tree sum.
    __shared__ float sRed[CIN][128];       // 8 KB
    sRed[cw][lane]      = acc0;
    sRed[cw][64 + lane] = acc1;
    __syncthreads();

    if (tid < 128) {
        float s = 0.0f;
        #pragma unroll
        for (int k = 0; k < CIN; ++k) s += sRed[k][tid];   // lanes 0..63 consecutive -> conflict-free
        const int row = r0 + (tid >> 6);
        const int col = tid & 63;
        out[((b * COUT + f) * HH + row) * WW + col] = s;
    }
}

extern "C" void kernel_launch(void* const* d_in, const int* in_sizes, int n_in,
                              void* d_out, int out_size, void* d_ws, size_t ws_size,
                              hipStream_t stream) {
    const float* x  = (const float*)d_in[0];
    const float* A  = (const float*)d_in[1];
    const float* Bc = (const float*)d_in[2];
    float* out = (float*)d_out;

    const int grid = BB * (HH / 2) * COUT;   // 4 * 32 * 16 = 2048 blocks
    KAConv_kernel<<<grid, 1024, 0, stream>>>(x, A, Bc, out);
}